// Round 3
// baseline (121.934 us; speedup 1.0000x reference)
//
#include <hip/hip_runtime.h>

// Rips 1-skeleton Euler characteristic curve, B=4096 pts in [0,1]^3.
// bin t = min(ceil(d*31.5), 63); out[k] = 4096 - (#edges with bin <= k).
// All d <= sqrt(3) < t_max=2 => every pair is an edge.
//
// Structure: init kernel zeroes g[0..63] (hist) + g[64] (block counter).
// Pair kernel: points staged in LDS as half4 (fp16 is safe: coord err 2.4e-4
// vs bin width 3.2e-2 and absmax threshold 1.7e5), each block owns rows
// {2b, 2b+1, 4094-2b, 4095-2b} = exactly 8190 pairs (perfect balance),
// 2 pairs per LDS point-load, 4-way bank-shifted per-wave LDS histograms,
// 64 global atomics per block to flush, last block finalizes (cumsum+write).

#define B_PTS 4096
#define STEPS 64
#define SCALE_F 31.5f
#define NBLK 1024
#define NTHR 256
#define NWAVES 4
#define NCOPY 4
#define CSTRIDE 65  // copy c shifts LDS bank by c -> same-bin atomics split across banks

typedef _Float16 half4_t __attribute__((ext_vector_type(4)));

__global__ __launch_bounds__(NTHR) void rips_init(int* __restrict__ g) {
    const int t = threadIdx.x;
    if (t < STEPS + 1) g[t] = 0;
}

__device__ __forceinline__ void acc_pair(float xi, float yi, float zi,
                                         float xj, float yj, float zj,
                                         int* h) {
    const float dx = xi - xj, dy = yi - yj, dz = zi - zj;
    const float d2 = dx * dx + dy * dy + dz * dz;
    int t = (int)ceilf(__builtin_amdgcn_sqrtf(d2) * SCALE_F);
    t = t > STEPS - 1 ? STEPS - 1 : t;
    atomicAdd(&h[t], 1);
}

__global__ __launch_bounds__(NTHR) void rips_pair(
    const float* __restrict__ x, int* __restrict__ g, float* __restrict__ out) {
    __shared__ half4_t pts[B_PTS];                 // 32 KB
    __shared__ int hist[NWAVES][NCOPY * CSTRIDE];  // 4.1 KB
    __shared__ int cnt[STEPS];
    __shared__ int is_last;

    const int tid = threadIdx.x;
    const int wave = tid >> 6;
    const int b = blockIdx.x;

    // Stage all points into LDS as fp16 xyz + pad (one ds_read_b64 per point later).
    for (int p = tid; p < B_PTS; p += NTHR) {
        const float xf = x[3 * p + 0], yf = x[3 * p + 1], zf = x[3 * p + 2];
        half4_t h = {(_Float16)xf, (_Float16)yf, (_Float16)zf, (_Float16)0.0f};
        pts[p] = h;
    }
    for (int k = tid; k < NWAVES * NCOPY * CSTRIDE; k += NTHR) (&hist[0][0])[k] = 0;
    __syncthreads();

    int* h0 = &hist[wave][(tid & 1) * CSTRIDE];
    int* h1 = &hist[wave][((tid & 1) + 2) * CSTRIDE];

    // Row group A: rows 2b, 2b+1.
    {
        const int i0 = 2 * b, i1 = 2 * b + 1;
        const half4_t p0 = pts[i0], p1 = pts[i1];
        const float x0 = (float)p0.x, y0 = (float)p0.y, z0 = (float)p0.z;
        const float x1 = (float)p1.x, y1 = (float)p1.y, z1 = (float)p1.z;
        for (int j = i1 + tid; j < B_PTS; j += NTHR) {
            const half4_t q = pts[j];
            const float xj = (float)q.x, yj = (float)q.y, zj = (float)q.z;
            acc_pair(x0, y0, z0, xj, yj, zj, h0);        // j > i0 always
            if (j > i1) acc_pair(x1, y1, z1, xj, yj, zj, h1);
        }
    }
    // Row group B: rows 4094-2b, 4095-2b.
    {
        const int i0 = B_PTS - 2 - 2 * b, i1 = B_PTS - 1 - 2 * b;
        const half4_t p0 = pts[i0], p1 = pts[i1];
        const float x0 = (float)p0.x, y0 = (float)p0.y, z0 = (float)p0.z;
        const float x1 = (float)p1.x, y1 = (float)p1.y, z1 = (float)p1.z;
        for (int j = i0 + 1 + tid; j < B_PTS; j += NTHR) {
            const half4_t q = pts[j];
            const float xj = (float)q.x, yj = (float)q.y, zj = (float)q.z;
            acc_pair(x0, y0, z0, xj, yj, zj, h0);        // j > i0 always
            if (j > i1) acc_pair(x1, y1, z1, xj, yj, zj, h1);
        }
    }
    __syncthreads();

    // Flush block histogram: one device atomic per bin.
    if (tid < STEPS) {
        int s = 0;
#pragma unroll
        for (int w = 0; w < NWAVES; ++w)
#pragma unroll
            for (int c = 0; c < NCOPY; ++c) s += hist[w][c * CSTRIDE + tid];
        atomicAdd(&g[tid], s);
    }
    __syncthreads();  // drains the flush atomics (waitcnt before barrier)
    __threadfence();
    if (tid == 0) {
        const int old = atomicAdd(&g[STEPS], 1);
        is_last = (old == NBLK - 1);
    }
    __syncthreads();

    if (is_last) {
        __threadfence();
        if (tid < STEPS) cnt[tid] = atomicAdd(&g[tid], 0);  // coherent read
        __syncthreads();
        if (tid == 0) {
            int acc = 0;
            for (int k = 0; k < STEPS; ++k) { acc += cnt[k]; cnt[k] = acc; }
        }
        __syncthreads();
        if (tid < STEPS) out[tid] = (float)B_PTS - (float)cnt[tid];
    }
}

extern "C" void kernel_launch(void* const* d_in, const int* in_sizes, int n_in,
                              void* d_out, int out_size, void* d_ws, size_t ws_size,
                              hipStream_t stream) {
    const float* x = (const float*)d_in[0];
    float* out = (float*)d_out;
    int* g = (int*)d_ws;  // [0..63] hist, [64] counter

    rips_init<<<1, NTHR, 0, stream>>>(g);
    rips_pair<<<NBLK, NTHR, 0, stream>>>(x, g, out);
}

// Round 4
// 66.141 us; speedup vs baseline: 1.8435x; 1.8435x over previous
//
#include <hip/hip_runtime.h>

// Rips 1-skeleton Euler characteristic curve, B=4096 pts in [0,1]^3.
// bin t = min(ceil(d*31.5), 63); out[k] = 4096 - (#edges with bin <= k).
// All d <= sqrt(3) < t_max=2 => every pair is an edge.
//
// K1: points staged in LDS as half4 (verified bit-exact in R3), block b owns
// rows {2b, 2b+1, 4094-2b, 4095-2b} = exactly 8190 pairs, 4-copy bank-shifted
// per-wave LDS histograms, block flushes its 64-bin hist with ONE coalesced
// 256 B plain store to part[b*64..] (no device atomics, no fences — R3's
// same-address atomic storm + threadfence L2-invalidates were the 72 us).
// K2: 1 block x 1024 threads reduces 1024x64 partials (fully coalesced),
// cumsum, write. Kernel-boundary coherence covers the plain stores.

#define B_PTS 4096
#define STEPS 64
#define SCALE_F 31.5f
#define NBLK 1024
#define NTHR 256
#define NWAVES 4
#define NCOPY 4
#define CSTRIDE 65  // copy c shifts LDS bank by c

typedef _Float16 half4_t __attribute__((ext_vector_type(4)));

__device__ __forceinline__ void acc_pair(float xi, float yi, float zi,
                                         float xj, float yj, float zj,
                                         int* h) {
    const float dx = xi - xj, dy = yi - yj, dz = zi - zj;
    const float d2 = dx * dx + dy * dy + dz * dz;
    int t = (int)ceilf(__builtin_amdgcn_sqrtf(d2) * SCALE_F);
    t = t > STEPS - 1 ? STEPS - 1 : t;
    atomicAdd(&h[t], 1);  // LDS atomic, wave-private histogram copy
}

__global__ __launch_bounds__(NTHR) void rips_pair(
    const float* __restrict__ x, int* __restrict__ part) {
    __shared__ half4_t pts[B_PTS];                 // 32 KB
    __shared__ int hist[NWAVES][NCOPY * CSTRIDE];  // 4.1 KB

    const int tid = threadIdx.x;
    const int wave = tid >> 6;
    const int b = blockIdx.x;

    for (int p = tid; p < B_PTS; p += NTHR) {
        const float xf = x[3 * p + 0], yf = x[3 * p + 1], zf = x[3 * p + 2];
        half4_t h = {(_Float16)xf, (_Float16)yf, (_Float16)zf, (_Float16)0.0f};
        pts[p] = h;
    }
    for (int k = tid; k < NWAVES * NCOPY * CSTRIDE; k += NTHR) (&hist[0][0])[k] = 0;
    __syncthreads();

    int* h0 = &hist[wave][(tid & 1) * CSTRIDE];
    int* h1 = &hist[wave][((tid & 1) + 2) * CSTRIDE];

    // Row group A: rows 2b, 2b+1.
    {
        const int i0 = 2 * b, i1 = 2 * b + 1;
        const half4_t p0 = pts[i0], p1 = pts[i1];
        const float x0 = (float)p0.x, y0 = (float)p0.y, z0 = (float)p0.z;
        const float x1 = (float)p1.x, y1 = (float)p1.y, z1 = (float)p1.z;
        for (int j = i1 + tid; j < B_PTS; j += NTHR) {
            const half4_t q = pts[j];
            const float xj = (float)q.x, yj = (float)q.y, zj = (float)q.z;
            acc_pair(x0, y0, z0, xj, yj, zj, h0);        // j > i0 always
            if (j > i1) acc_pair(x1, y1, z1, xj, yj, zj, h1);
        }
    }
    // Row group B: rows 4094-2b, 4095-2b.
    {
        const int i0 = B_PTS - 2 - 2 * b, i1 = B_PTS - 1 - 2 * b;
        const half4_t p0 = pts[i0], p1 = pts[i1];
        const float x0 = (float)p0.x, y0 = (float)p0.y, z0 = (float)p0.z;
        const float x1 = (float)p1.x, y1 = (float)p1.y, z1 = (float)p1.z;
        for (int j = i0 + 1 + tid; j < B_PTS; j += NTHR) {
            const half4_t q = pts[j];
            const float xj = (float)q.x, yj = (float)q.y, zj = (float)q.z;
            acc_pair(x0, y0, z0, xj, yj, zj, h0);        // j > i0 always
            if (j > i1) acc_pair(x1, y1, z1, xj, yj, zj, h1);
        }
    }
    __syncthreads();

    // Flush: one coalesced 256 B plain store per block. No atomics, no fence.
    if (tid < STEPS) {
        int s = 0;
#pragma unroll
        for (int w = 0; w < NWAVES; ++w)
#pragma unroll
            for (int c = 0; c < NCOPY; ++c) s += hist[w][c * CSTRIDE + tid];
        part[b * STEPS + tid] = s;
    }
}

#define RTHR 1024
#define RWAVES (RTHR / 64)  // 16

__global__ __launch_bounds__(RTHR) void rips_reduce(
    const int* __restrict__ part, float* __restrict__ out) {
    __shared__ int psum[RWAVES][STEPS];
    __shared__ int cnt[STEPS];
    const int t = threadIdx.x;
    const int bin = t & 63, q = t >> 6;

    // Wave q sums blocks [q*64, (q+1)*64); each load instr = contiguous 256 B.
    const int per = NBLK / RWAVES;  // 64
    const int* p = part + q * per * STEPS + bin;
    int s = 0;
#pragma unroll 8
    for (int i = 0; i < per; ++i) s += p[i * STEPS];
    psum[q][bin] = s;
    __syncthreads();

    if (t < STEPS) {
        int tot = 0;
#pragma unroll
        for (int w = 0; w < RWAVES; ++w) tot += psum[w][t];
        cnt[t] = tot;
    }
    __syncthreads();
    if (t == 0) {
        int acc = 0;
        for (int k = 0; k < STEPS; ++k) { acc += cnt[k]; cnt[k] = acc; }
    }
    __syncthreads();
    if (t < STEPS) out[t] = (float)B_PTS - (float)cnt[t];
}

extern "C" void kernel_launch(void* const* d_in, const int* in_sizes, int n_in,
                              void* d_out, int out_size, void* d_ws, size_t ws_size,
                              hipStream_t stream) {
    const float* x = (const float*)d_in[0];
    float* out = (float*)d_out;
    int* part = (int*)d_ws;  // NBLK * 64 ints = 256 KB

    rips_pair<<<NBLK, NTHR, 0, stream>>>(x, part);
    rips_reduce<<<1, RTHR, 0, stream>>>(part, out);
}

// Round 5
// 60.283 us; speedup vs baseline: 2.0227x; 1.0972x over previous
//
#include <hip/hip_runtime.h>

// Rips 1-skeleton Euler characteristic curve, B=4096 pts in [0,1]^3.
// bin t = min(ceil(d*31.5), 63); out[k] = 4096 - (#edges with bin <= k).
// All d <= sqrt(3) < t_max=2 => every pair is an edge.
//
// K1 (512 blocks x 512 thr): all points staged in LDS as half4 (fp16 coords
// verified bit-exact R3/R4; err 2.4e-4 << bin width 3.2e-2, threshold 1.7e5).
// Block b owns 8 rows {4b..4b+3} U {4092-4b..4095-4b} = exactly 16380 pairs.
// One ds_read_b64 per j feeds 4 pairs. 12 intra-group pairs done by lanes
// 0-11 so main loops are predicate-free. Per-wave 4-copy bank-shifted LDS
// histograms, atomic copy rotated by (pair + tid&3)&3 -> <=16 lanes/copy.
// Flush = one coalesced 256 B plain store per block (no device atomics).
// K2: 1 block x 1024 thr reduces 512x64 partials, cumsum, write.

#define B_PTS 4096
#define STEPS 64
#define SCALE_F 31.5f
#define NBLK 512
#define NTHR 512
#define NWAVES (NTHR / 64)   // 8
#define NCOPY 4
#define CSTRIDE 65           // copy c shifts LDS bank by c

typedef _Float16 half4_t __attribute__((ext_vector_type(4)));
typedef _Float16 half8_t __attribute__((ext_vector_type(8)));

__device__ __forceinline__ void acc_pair(float xi, float yi, float zi,
                                         float xj, float yj, float zj,
                                         int* h) {
    const float dx = xi - xj, dy = yi - yj, dz = zi - zj;
    const float d2 = dx * dx + dy * dy + dz * dz;
    int t = (int)ceilf(__builtin_amdgcn_sqrtf(d2) * SCALE_F);
    t = t > STEPS - 1 ? STEPS - 1 : t;
    atomicAdd(&h[t], 1);  // LDS atomic into wave-private copy
}

__global__ __launch_bounds__(NTHR) void rips_pair(
    const float* __restrict__ x, int* __restrict__ part) {
    __shared__ half4_t pts[B_PTS];                 // 32 KB
    __shared__ int hist[NWAVES][NCOPY * CSTRIDE];  // 8.1 KB

    const int tid = threadIdx.x;
    const int wave = tid >> 6;
    const int b = blockIdx.x;

    // Stage: thread handles 4 consecutive points = 3 float4 loads -> 2 b128 LDS writes.
    {
        const float4* x4 = (const float4*)x;
#pragma unroll
        for (int k = 0; k < B_PTS / (4 * NTHR); ++k) {   // 2 iters
            const int m = tid + k * NTHR;                 // points 4m..4m+3
            const float4 f0 = x4[3 * m + 0];
            const float4 f1 = x4[3 * m + 1];
            const float4 f2 = x4[3 * m + 2];
            half8_t h01 = {(_Float16)f0.x, (_Float16)f0.y, (_Float16)f0.z, (_Float16)0.f,
                           (_Float16)f0.w, (_Float16)f1.x, (_Float16)f1.y, (_Float16)0.f};
            half8_t h23 = {(_Float16)f1.z, (_Float16)f1.w, (_Float16)f2.x, (_Float16)0.f,
                           (_Float16)f2.y, (_Float16)f2.z, (_Float16)f2.w, (_Float16)0.f};
            *(half8_t*)&pts[4 * m + 0] = h01;
            *(half8_t*)&pts[4 * m + 2] = h23;
        }
    }
    for (int k = tid; k < NWAVES * NCOPY * CSTRIDE; k += NTHR) (&hist[0][0])[k] = 0;
    __syncthreads();

    // Rotated histogram-copy pointers: pair r -> copy (r + tid&3)&3.
    int* hw = &hist[wave][0];
    const int c0 = tid & 3;
    int* h0 = hw + (((0 + c0) & 3) * CSTRIDE);
    int* h1 = hw + (((1 + c0) & 3) * CSTRIDE);
    int* h2 = hw + (((2 + c0) & 3) * CSTRIDE);
    int* h3 = hw + (((3 + c0) & 3) * CSTRIDE);

    // 12 intra-group pairs (6 top + 6 bottom), lanes 0..11 of wave 0.
    if (tid < 12) {
        const int ri[6] = {0, 0, 0, 1, 1, 2};
        const int si[6] = {1, 2, 3, 2, 3, 3};
        const int k = tid < 6 ? tid : tid - 6;
        const int base = tid < 6 ? 4 * b : B_PTS - 4 - 4 * b;
        const half4_t pi = pts[base + ri[k]];
        const half4_t pj = pts[base + si[k]];
        acc_pair((float)pi.x, (float)pi.y, (float)pi.z,
                 (float)pj.x, (float)pj.y, (float)pj.z, h0);
    }

    // Top group: rows 4b..4b+3, j in [4b+4, 4096) predicate-free.
    {
        const int i0 = 4 * b;
        float X[4], Y[4], Z[4];
#pragma unroll
        for (int r = 0; r < 4; ++r) {
            const half4_t p = pts[i0 + r];  // wave-uniform -> broadcast
            X[r] = (float)p.x; Y[r] = (float)p.y; Z[r] = (float)p.z;
        }
        for (int j = i0 + 4 + tid; j < B_PTS; j += NTHR) {
            const half4_t q = pts[j];
            const float xj = (float)q.x, yj = (float)q.y, zj = (float)q.z;
            acc_pair(X[0], Y[0], Z[0], xj, yj, zj, h0);
            acc_pair(X[1], Y[1], Z[1], xj, yj, zj, h1);
            acc_pair(X[2], Y[2], Z[2], xj, yj, zj, h2);
            acc_pair(X[3], Y[3], Z[3], xj, yj, zj, h3);
        }
    }
    // Bottom group: rows 4092-4b..4095-4b, j in [4096-4b, 4096) predicate-free.
    {
        const int i0 = B_PTS - 4 - 4 * b;
        float X[4], Y[4], Z[4];
#pragma unroll
        for (int r = 0; r < 4; ++r) {
            const half4_t p = pts[i0 + r];
            X[r] = (float)p.x; Y[r] = (float)p.y; Z[r] = (float)p.z;
        }
        for (int j = i0 + 4 + tid; j < B_PTS; j += NTHR) {
            const half4_t q = pts[j];
            const float xj = (float)q.x, yj = (float)q.y, zj = (float)q.z;
            acc_pair(X[0], Y[0], Z[0], xj, yj, zj, h0);
            acc_pair(X[1], Y[1], Z[1], xj, yj, zj, h1);
            acc_pair(X[2], Y[2], Z[2], xj, yj, zj, h2);
            acc_pair(X[3], Y[3], Z[3], xj, yj, zj, h3);
        }
    }
    __syncthreads();

    // Flush: one coalesced 256 B plain store per block.
    if (tid < STEPS) {
        int s = 0;
#pragma unroll
        for (int w = 0; w < NWAVES; ++w)
#pragma unroll
            for (int c = 0; c < NCOPY; ++c) s += hist[w][c * CSTRIDE + tid];
        part[b * STEPS + tid] = s;
    }
}

#define RTHR 1024
#define RWAVES (RTHR / 64)  // 16

__global__ __launch_bounds__(RTHR) void rips_reduce(
    const int* __restrict__ part, float* __restrict__ out) {
    __shared__ int psum[RWAVES][STEPS];
    __shared__ int cnt[STEPS];
    const int t = threadIdx.x;
    const int bin = t & 63, q = t >> 6;

    const int per = NBLK / RWAVES;  // 32 blocks per wave
    const int* p = part + q * per * STEPS + bin;
    int s = 0;
#pragma unroll 8
    for (int i = 0; i < per; ++i) s += p[i * STEPS];
    psum[q][bin] = s;
    __syncthreads();

    if (t < STEPS) {
        int tot = 0;
#pragma unroll
        for (int w = 0; w < RWAVES; ++w) tot += psum[w][t];
        cnt[t] = tot;
    }
    __syncthreads();
    if (t == 0) {
        int acc = 0;
        for (int k = 0; k < STEPS; ++k) { acc += cnt[k]; cnt[k] = acc; }
    }
    __syncthreads();
    if (t < STEPS) out[t] = (float)B_PTS - (float)cnt[t];
}

extern "C" void kernel_launch(void* const* d_in, const int* in_sizes, int n_in,
                              void* d_out, int out_size, void* d_ws, size_t ws_size,
                              hipStream_t stream) {
    const float* x = (const float*)d_in[0];
    float* out = (float*)d_out;
    int* part = (int*)d_ws;  // NBLK * 64 ints = 128 KB

    rips_pair<<<NBLK, NTHR, 0, stream>>>(x, part);
    rips_reduce<<<1, RTHR, 0, stream>>>(part, out);
}